// Round 2
// baseline (159.214 us; speedup 1.0000x reference)
//
#include <hip/hip_runtime.h>

// PointWarping: B=2, C=3, N=8192. Brute-force K=3 NN + inverse-distance flow interp.
// Round 2: 32-way candidate split, Q=4 queries/thread (amortizes LDS reads 4x),
// branchless top-3 insert via v_med3_f32 + cndmask index tracking.

#define NPTS   8192
#define TILE   2048
#define NTILES (NPTS / TILE)
#define BLOCK  256
#define GROUP  32
#define NGRP   (BLOCK / GROUP)   // 8 query-groups per block
#define Q      4                 // queries per thread
#define QPB    (NGRP * Q)        // 32 queries per block
#define MSTR   97                // merge stride (32*3 + 1 pad -> conflict-free)
#define EPSV   1e-10f

__global__ __launch_bounds__(BLOCK, 2)
void pointwarp_kernel(const float* __restrict__ xyz1,
                      const float* __restrict__ xyz2,
                      const float* __restrict__ flow1,
                      float* __restrict__ out) {
    __shared__ float4 s_pts[TILE];          // 32 KB candidates (x,y,z,pad)
    __shared__ float  s_md[QPB * MSTR];     // partial top-3 dists
    __shared__ int    s_mi[QPB * MSTR];     // partial top-3 idxs

    const int tid = threadIdx.x;
    const int qg  = tid >> 5;               // query group [0,8)
    const int t   = tid & 31;               // candidate lane [0,32)
    const int blocksPerB = NPTS / QPB;      // 256
    const int b     = blockIdx.x / blocksPerB;
    const int qblk  = (blockIdx.x % blocksPerB) * QPB;
    const int qbase = qblk + qg * Q;

    const float* x1 = xyz1 + (size_t)b * 3 * NPTS;
    const float* x2 = xyz2 + (size_t)b * 3 * NPTS;
    const float* f1 = flow1 + (size_t)b * 3 * NPTS;

    float qx[Q], qy[Q], qz[Q], e0[Q], e1[Q], e2[Q];
    int   i0[Q], i1[Q], i2[Q];
    #pragma unroll
    for (int i = 0; i < Q; ++i) {
        qx[i] = x2[0*NPTS + qbase + i];
        qy[i] = x2[1*NPTS + qbase + i];
        qz[i] = x2[2*NPTS + qbase + i];
        e0[i] = e1[i] = e2[i] = 1e30f;
        i0[i] = i1[i] = i2[i] = 0;
    }

    for (int tile = 0; tile < NTILES; ++tile) {
        const int base = tile * TILE;
        // stage: float4 global loads, 4 candidates per iteration
        for (int g4 = tid; g4 < TILE/4; g4 += BLOCK) {
            const int n1 = base + g4*4;
            const float4 ax = *(const float4*)&x1[0*NPTS + n1];
            const float4 ay = *(const float4*)&x1[1*NPTS + n1];
            const float4 az = *(const float4*)&x1[2*NPTS + n1];
            const float4 fx = *(const float4*)&f1[0*NPTS + n1];
            const float4 fy = *(const float4*)&f1[1*NPTS + n1];
            const float4 fz = *(const float4*)&f1[2*NPTS + n1];
            s_pts[g4*4+0] = make_float4(ax.x+fx.x, ay.x+fy.x, az.x+fz.x, 0.f);
            s_pts[g4*4+1] = make_float4(ax.y+fx.y, ay.y+fy.y, az.y+fz.y, 0.f);
            s_pts[g4*4+2] = make_float4(ax.z+fx.z, ay.z+fy.z, az.z+fz.z, 0.f);
            s_pts[g4*4+3] = make_float4(ax.w+fx.w, ay.w+fy.w, az.w+fz.w, 0.f);
        }
        __syncthreads();

        // scan: thread t covers jj = j*32+t; each LDS read feeds Q=4 queries
        #pragma unroll 4
        for (int j = 0; j < TILE/GROUP; ++j) {
            const int jj  = j * GROUP + t;
            const float4 p = s_pts[jj];
            const int idx = base + jj;
            #pragma unroll
            for (int i = 0; i < Q; ++i) {
                const float dx = p.x - qx[i];
                const float dy = p.y - qy[i];
                const float dz = p.z - qz[i];
                const float d  = dx*dx + dy*dy + dz*dz;
                const bool c0 = d < e0[i];
                const bool c1 = d < e1[i];
                const bool c2 = d < e2[i];
                // branchless sorted insert (e0<=e1<=e2 invariant)
                e2[i] = __builtin_amdgcn_fmed3f(d, e1[i], e2[i]);
                e1[i] = __builtin_amdgcn_fmed3f(d, e0[i], e1[i]);
                e0[i] = fminf(d, e0[i]);
                i2[i] = c1 ? i1[i] : (c2 ? idx : i2[i]);
                i1[i] = c0 ? i0[i] : (c1 ? idx : i1[i]);
                i0[i] = c0 ? idx   : i0[i];
            }
        }
        __syncthreads();
    }

    // publish per-thread partial top-3 (32 partials per query)
    #pragma unroll
    for (int i = 0; i < Q; ++i) {
        const int q = qg * Q + i;
        const int o = q * MSTR + t * 3;
        s_md[o+0] = e0[i]; s_mi[o+0] = i0[i];
        s_md[o+1] = e1[i]; s_mi[o+1] = i1[i];
        s_md[o+2] = e2[i]; s_mi[o+2] = i2[i];
    }
    __syncthreads();

    // one merger thread per query (threads 0..31)
    if (tid < QPB) {
        float m0 = 1e30f, m1 = 1e30f, m2 = 1e30f;
        int   j0 = 0, j1 = 0, j2 = 0;
        const int sb = tid * MSTR;
        for (int k = 0; k < GROUP * 3; ++k) {
            const float d  = s_md[sb + k];
            const int  idx = s_mi[sb + k];
            const bool c0 = d < m0;
            const bool c1 = d < m1;
            const bool c2 = d < m2;
            m2 = __builtin_amdgcn_fmed3f(d, m1, m2);
            m1 = __builtin_amdgcn_fmed3f(d, m0, m1);
            m0 = fminf(d, m0);
            j2 = c1 ? j1 : (c2 ? idx : j2);
            j1 = c0 ? j0 : (c1 ? idx : j1);
            j0 = c0 ? idx : j0;
        }
        // inverse-distance weights (selection was on exact d^2)
        float w0 = 1.0f / fmaxf(sqrtf(m0), EPSV);
        float w1 = 1.0f / fmaxf(sqrtf(m1), EPSV);
        float w2 = 1.0f / fmaxf(sqrtf(m2), EPSV);
        const float ws = w0 + w1 + w2;
        w0 /= ws; w1 /= ws; w2 /= ws;

        const int n2 = qblk + tid;
        float* o = out + (size_t)b * 3 * NPTS;
        #pragma unroll
        for (int c = 0; c < 3; ++c) {
            const float fl = w0 * f1[c*NPTS + j0]
                           + w1 * f1[c*NPTS + j1]
                           + w2 * f1[c*NPTS + j2];
            o[c*NPTS + n2] = x2[c*NPTS + n2] - fl;
        }
    }
}

extern "C" void kernel_launch(void* const* d_in, const int* in_sizes, int n_in,
                              void* d_out, int out_size, void* d_ws, size_t ws_size,
                              hipStream_t stream) {
    const float* xyz1  = (const float*)d_in[0];
    const float* xyz2  = (const float*)d_in[1];
    const float* flow1 = (const float*)d_in[2];
    float* out = (float*)d_out;

    const int B = in_sizes[0] / (3 * NPTS);     // = 2
    const int grid = B * (NPTS / QPB);          // 512 blocks
    pointwarp_kernel<<<grid, BLOCK, 0, stream>>>(xyz1, xyz2, flow1, out);
}

// Round 3
// 145.017 us; speedup vs baseline: 1.0979x; 1.0979x over previous
//
#include <hip/hip_runtime.h>

// PointWarping: B=2, C=3, N=8192. Brute-force K=3 NN + inverse-distance flow interp.
// Round 3: GROUP=64 (full wave shares Q=4 queries, lanes split candidates),
// QPB=16 -> grid=1024 blocks = 4 blocks/CU (fixes grid-limited occupancy).
// Merge = in-register shfl_xor butterfly (no merge LDS, no extra syncthreads).
// Distance key d' = |p|^2 - 2 p.q via 3 FMAs (|p|^2 staged in float4.w).

#define NPTS   8192
#define TILE   2048
#define NTILES (NPTS / TILE)
#define BLOCK  256
#define GROUP  64
#define Q      4
#define QPB    ((BLOCK / GROUP) * Q)   // 16 queries per block
#define EPSV   1e-10f

__device__ __forceinline__ void insert3(float d, int idx,
                                        float& m0, float& m1, float& m2,
                                        int& j0, int& j1, int& j2) {
    const bool c0 = d < m0;
    const bool c1 = d < m1;
    const bool c2 = d < m2;
    m2 = __builtin_amdgcn_fmed3f(d, m1, m2);
    m1 = __builtin_amdgcn_fmed3f(d, m0, m1);
    m0 = fminf(d, m0);
    j2 = c1 ? j1 : (c2 ? idx : j2);
    j1 = c0 ? j0 : (c1 ? idx : j1);
    j0 = c0 ? idx : j0;
}

__global__ __launch_bounds__(BLOCK, 4)
void pointwarp_kernel(const float* __restrict__ xyz1,
                      const float* __restrict__ xyz2,
                      const float* __restrict__ flow1,
                      float* __restrict__ out) {
    __shared__ float4 s_pts[TILE];          // 32 KB: (x, y, z, |p|^2)

    const int tid = threadIdx.x;
    const int w   = tid >> 6;               // wave in block [0,4)
    const int t   = tid & 63;               // lane [0,64)
    const int blocksPerB = NPTS / QPB;      // 512
    const int b     = blockIdx.x / blocksPerB;
    const int qblk  = (blockIdx.x % blocksPerB) * QPB;
    const int qbase = qblk + w * Q;         // this wave's 4 queries

    const float* x1 = xyz1 + (size_t)b * 3 * NPTS;
    const float* x2 = xyz2 + (size_t)b * 3 * NPTS;
    const float* f1 = flow1 + (size_t)b * 3 * NPTS;

    float nqx[Q], nqy[Q], nqz[Q], qq[Q], e0[Q], e1[Q], e2[Q];
    int   i0[Q], i1[Q], i2[Q];
    #pragma unroll
    for (int i = 0; i < Q; ++i) {
        const float qx = x2[0*NPTS + qbase + i];
        const float qy = x2[1*NPTS + qbase + i];
        const float qz = x2[2*NPTS + qbase + i];
        nqx[i] = -2.0f * qx; nqy[i] = -2.0f * qy; nqz[i] = -2.0f * qz;
        qq[i]  = qx*qx + qy*qy + qz*qz;
        e0[i] = e1[i] = e2[i] = 1e30f;
        i0[i] = i1[i] = i2[i] = 0;
    }

    for (int tile = 0; tile < NTILES; ++tile) {
        const int base = tile * TILE;
        // stage: float4 global loads; w slot = |p|^2 (amortized over 16 queries)
        for (int g4 = tid; g4 < TILE/4; g4 += BLOCK) {
            const int n1 = base + g4*4;
            const float4 ax = *(const float4*)&x1[0*NPTS + n1];
            const float4 ay = *(const float4*)&x1[1*NPTS + n1];
            const float4 az = *(const float4*)&x1[2*NPTS + n1];
            const float4 fx = *(const float4*)&f1[0*NPTS + n1];
            const float4 fy = *(const float4*)&f1[1*NPTS + n1];
            const float4 fz = *(const float4*)&f1[2*NPTS + n1];
            float px, py, pz;
            px = ax.x+fx.x; py = ay.x+fy.x; pz = az.x+fz.x;
            s_pts[g4*4+0] = make_float4(px, py, pz, px*px + py*py + pz*pz);
            px = ax.y+fx.y; py = ay.y+fy.y; pz = az.y+fz.y;
            s_pts[g4*4+1] = make_float4(px, py, pz, px*px + py*py + pz*pz);
            px = ax.z+fx.z; py = ay.z+fy.z; pz = az.z+fz.z;
            s_pts[g4*4+2] = make_float4(px, py, pz, px*px + py*py + pz*pz);
            px = ax.w+fx.w; py = ay.w+fy.w; pz = az.w+fz.w;
            s_pts[g4*4+3] = make_float4(px, py, pz, px*px + py*py + pz*pz);
        }
        __syncthreads();

        // scan: lane t covers jj = j*64+t; one b128 read feeds Q=4 queries
        #pragma unroll 4
        for (int j = 0; j < TILE/GROUP; ++j) {
            const int jj  = j * GROUP + t;
            const float4 p = s_pts[jj];
            const int idx = base + jj;
            #pragma unroll
            for (int i = 0; i < Q; ++i) {
                // d' = |p|^2 - 2 p.q  (3 FMAs; monotone in true squared dist)
                float d = fmaf(p.z, nqz[i], p.w);
                d = fmaf(p.y, nqy[i], d);
                d = fmaf(p.x, nqx[i], d);
                insert3(d, idx, e0[i], e1[i], e2[i], i0[i], i1[i], i2[i]);
            }
        }
        __syncthreads();
    }

    // wave-level butterfly merge of the 64 partial top-3 lists (per query)
    #pragma unroll
    for (int step = 1; step < 64; step <<= 1) {
        #pragma unroll
        for (int i = 0; i < Q; ++i) {
            const float b0 = __shfl_xor(e0[i], step, 64);
            const float b1 = __shfl_xor(e1[i], step, 64);
            const float b2 = __shfl_xor(e2[i], step, 64);
            const int   a0 = __shfl_xor(i0[i], step, 64);
            const int   a1 = __shfl_xor(i1[i], step, 64);
            const int   a2 = __shfl_xor(i2[i], step, 64);
            insert3(b0, a0, e0[i], e1[i], e2[i], i0[i], i1[i], i2[i]);
            insert3(b1, a1, e0[i], e1[i], e2[i], i0[i], i1[i], i2[i]);
            insert3(b2, a2, e0[i], e1[i], e2[i], i0[i], i1[i], i2[i]);
        }
    }

    // lanes 0..Q-1 of each wave write one query each
    if (t < Q) {
        const int i  = t;
        const int n2 = qbase + i;
        const float d0 = fmaxf(e0[i] + qq[i], 0.0f);
        const float d1 = fmaxf(e1[i] + qq[i], 0.0f);
        const float d2 = fmaxf(e2[i] + qq[i], 0.0f);
        float w0 = 1.0f / fmaxf(sqrtf(d0), EPSV);
        float w1 = 1.0f / fmaxf(sqrtf(d1), EPSV);
        float w2 = 1.0f / fmaxf(sqrtf(d2), EPSV);
        const float ws = w0 + w1 + w2;
        w0 /= ws; w1 /= ws; w2 /= ws;

        const int j0 = i0[i], j1 = i1[i], j2 = i2[i];
        float* o = out + (size_t)b * 3 * NPTS;
        #pragma unroll
        for (int c = 0; c < 3; ++c) {
            const float fl = w0 * f1[c*NPTS + j0]
                           + w1 * f1[c*NPTS + j1]
                           + w2 * f1[c*NPTS + j2];
            o[c*NPTS + n2] = x2[c*NPTS + n2] - fl;
        }
    }
}

extern "C" void kernel_launch(void* const* d_in, const int* in_sizes, int n_in,
                              void* d_out, int out_size, void* d_ws, size_t ws_size,
                              hipStream_t stream) {
    const float* xyz1  = (const float*)d_in[0];
    const float* xyz2  = (const float*)d_in[1];
    const float* flow1 = (const float*)d_in[2];
    float* out = (float*)d_out;

    const int B = in_sizes[0] / (3 * NPTS);     // = 2
    const int grid = B * (NPTS / QPB);          // 1024 blocks = 4 per CU
    pointwarp_kernel<<<grid, BLOCK, 0, stream>>>(xyz1, xyz2, flow1, out);
}

// Round 4
// 112.567 us; speedup vs baseline: 1.4144x; 1.2883x over previous
//
#include <hip/hip_runtime.h>

// PointWarping: B=2, C=3, N=8192. Brute-force K=3 NN + inverse-distance flow interp.
// Round 4: SoA LDS (float2 xy + float z) -> conflict-free reads/writes;
// direct-form distance (no cancellation); packed sort keys (d | row-index)
// so the hot loop's top-3 insert is 3 sort ops, no compares/cndmasks.
// Index low-6-bits = lane id (implicit); exact distances recomputed in epilogue.

#define NPTS   8192
#define TILE   2048
#define NTILES (NPTS / TILE)
#define BLOCK  256
#define GROUP  64
#define Q      4
#define QPB    ((BLOCK / GROUP) * Q)   // 16 queries per block
#define KMASK  0xFFFFFF80              // keep 25 msbs of d; low 7 bits = row j
#define EPSV   1e-10f

__device__ __forceinline__ void insert3_idx(float k, int idx,
                                            float& m0, float& m1, float& m2,
                                            int& j0, int& j1, int& j2) {
    const bool c0 = k < m0;
    const bool c1 = k < m1;
    const bool c2 = k < m2;
    m2 = __builtin_amdgcn_fmed3f(k, m1, m2);
    m1 = __builtin_amdgcn_fmed3f(k, m0, m1);
    m0 = fminf(k, m0);
    j2 = c1 ? j1 : (c2 ? idx : j2);
    j1 = c0 ? j0 : (c1 ? idx : j1);
    j0 = c0 ? idx : j0;
}

__global__ __launch_bounds__(BLOCK, 4)
void pointwarp_kernel(const float* __restrict__ xyz1,
                      const float* __restrict__ xyz2,
                      const float* __restrict__ flow1,
                      float* __restrict__ out) {
    __shared__ float2 s_xy[TILE];   // 16 KB
    __shared__ float  s_z[TILE];    // 8 KB

    const int tid = threadIdx.x;
    const int w   = tid >> 6;               // wave in block [0,4)
    const int t   = tid & 63;               // lane [0,64)
    const int blocksPerB = NPTS / QPB;      // 512
    const int b     = blockIdx.x / blocksPerB;
    const int qblk  = (blockIdx.x % blocksPerB) * QPB;
    const int qbase = qblk + w * Q;         // this wave's 4 queries

    const float* x1 = xyz1 + (size_t)b * 3 * NPTS;
    const float* x2 = xyz2 + (size_t)b * 3 * NPTS;
    const float* f1 = flow1 + (size_t)b * 3 * NPTS;

    float qx[Q], qy[Q], qz[Q], k0[Q], k1[Q], k2[Q];
    #pragma unroll
    for (int i = 0; i < Q; ++i) {
        qx[i] = x2[0*NPTS + qbase + i];
        qy[i] = x2[1*NPTS + qbase + i];
        qz[i] = x2[2*NPTS + qbase + i];
        k0[i] = k1[i] = k2[i] = 3e38f;
    }

    for (int tile = 0; tile < NTILES; ++tile) {
        const int base = tile * TILE;
        // stage one point per thread-iteration: coalesced b32 global loads,
        // stride-4/8 LDS writes (conflict-free)
        for (int j = tid; j < TILE; j += BLOCK) {
            const int n1 = base + j;
            const float px = x1[0*NPTS + n1] + f1[0*NPTS + n1];
            const float py = x1[1*NPTS + n1] + f1[1*NPTS + n1];
            const float pz = x1[2*NPTS + n1] + f1[2*NPTS + n1];
            s_xy[j] = make_float2(px, py);
            s_z[j]  = pz;
        }
        __syncthreads();

        // scan: lane t covers jj = j*64+t; key = trunc(d) | row  (row = jg)
        #pragma unroll 4
        for (int j = 0; j < TILE/GROUP; ++j) {
            const int jj = j * GROUP + t;
            const int jg = tile * (TILE/GROUP) + j;   // wave-uniform row id [0,128)
            const float2 pxy = s_xy[jj];
            const float  pz  = s_z[jj];
            #pragma unroll
            for (int i = 0; i < Q; ++i) {
                const float dx = pxy.x - qx[i];
                const float dy = pxy.y - qy[i];
                const float dz = pz    - qz[i];
                const float d  = fmaf(dx, dx, fmaf(dy, dy, dz*dz));
                const float k  = __int_as_float((__float_as_int(d) & KMASK) | jg);
                k2[i] = __builtin_amdgcn_fmed3f(k, k1[i], k2[i]);
                k1[i] = __builtin_amdgcn_fmed3f(k, k0[i], k1[i]);
                k0[i] = fminf(k, k0[i]);
            }
        }
        __syncthreads();
    }

    // unpack row -> full candidate index (low 6 bits = lane id)
    int i0[Q], i1[Q], i2[Q];
    #pragma unroll
    for (int i = 0; i < Q; ++i) {
        i0[i] = ((__float_as_int(k0[i]) & 0x7F) << 6) | t;
        i1[i] = ((__float_as_int(k1[i]) & 0x7F) << 6) | t;
        i2[i] = ((__float_as_int(k2[i]) & 0x7F) << 6) | t;
    }

    // wave butterfly merge of 64 partial top-3 lists (tail-only cost)
    #pragma unroll
    for (int step = 1; step < 64; step <<= 1) {
        #pragma unroll
        for (int i = 0; i < Q; ++i) {
            const float b0 = __shfl_xor(k0[i], step, 64);
            const float b1 = __shfl_xor(k1[i], step, 64);
            const float b2 = __shfl_xor(k2[i], step, 64);
            const int   a0 = __shfl_xor(i0[i], step, 64);
            const int   a1 = __shfl_xor(i1[i], step, 64);
            const int   a2 = __shfl_xor(i2[i], step, 64);
            insert3_idx(b0, a0, k0[i], k1[i], k2[i], i0[i], i1[i], i2[i]);
            insert3_idx(b1, a1, k0[i], k1[i], k2[i], i0[i], i1[i], i2[i]);
            insert3_idx(b2, a2, k0[i], k1[i], k2[i], i0[i], i1[i], i2[i]);
        }
    }

    // lanes 0..Q-1: exact distances for the 3 winners, weights, output
    if (t < Q) {
        #pragma unroll
        for (int i = 0; i < Q; ++i) {
            if (t == i) {
                const int n2 = qbase + i;
                const int j0 = i0[i], j1 = i1[i], j2 = i2[i];
                float dd[3];
                const int js[3] = {j0, j1, j2};
                #pragma unroll
                for (int s = 0; s < 3; ++s) {
                    const int jn = js[s];
                    const float px = x1[0*NPTS + jn] + f1[0*NPTS + jn];
                    const float py = x1[1*NPTS + jn] + f1[1*NPTS + jn];
                    const float pz = x1[2*NPTS + jn] + f1[2*NPTS + jn];
                    const float dx = px - qx[i], dy = py - qy[i], dz = pz - qz[i];
                    dd[s] = fmaf(dx, dx, fmaf(dy, dy, dz*dz));
                }
                float w0 = 1.0f / fmaxf(sqrtf(dd[0]), EPSV);
                float w1 = 1.0f / fmaxf(sqrtf(dd[1]), EPSV);
                float w2 = 1.0f / fmaxf(sqrtf(dd[2]), EPSV);
                const float ws = w0 + w1 + w2;
                w0 /= ws; w1 /= ws; w2 /= ws;

                float* o = out + (size_t)b * 3 * NPTS;
                #pragma unroll
                for (int c = 0; c < 3; ++c) {
                    const float fl = w0 * f1[c*NPTS + j0]
                                   + w1 * f1[c*NPTS + j1]
                                   + w2 * f1[c*NPTS + j2];
                    o[c*NPTS + n2] = x2[c*NPTS + n2] - fl;
                }
            }
        }
    }
}

extern "C" void kernel_launch(void* const* d_in, const int* in_sizes, int n_in,
                              void* d_out, int out_size, void* d_ws, size_t ws_size,
                              hipStream_t stream) {
    const float* xyz1  = (const float*)d_in[0];
    const float* xyz2  = (const float*)d_in[1];
    const float* flow1 = (const float*)d_in[2];
    float* out = (float*)d_out;

    const int B = in_sizes[0] / (3 * NPTS);     // = 2
    const int grid = B * (NPTS / QPB);          // 1024 blocks = 4 per CU
    pointwarp_kernel<<<grid, BLOCK, 0, stream>>>(xyz1, xyz2, flow1, out);
}

// Round 6
// 104.200 us; speedup vs baseline: 1.5280x; 1.0803x over previous
//
#include <hip/hip_runtime.h>

// PointWarping: B=2, C=3, N=8192. Brute-force K=3 NN + inverse-distance flow interp.
// Round 6: identical to round 5 except the readfirstlane float bug is fixed
// (round 5 passed a float to __builtin_amdgcn_readfirstlane(int) -> implicit
// truncating conversion corrupted every query coordinate).
// Structure: pre-kernel writes warped points (x1+f1) as float4 into d_ws;
// hot loop reads them with coalesced global_load_dwordx4 (L2-resident,
// 128 KB/batch). Queries wave-uniform in SGPRs; candidates split 2-way across
// wave pairs -> grid 2048 blocks = 8 blocks/CU = 8 waves/SIMD.
// Packed sort keys (25-bit d | 7-bit row), exact epilogue recompute.

#define NPTS   8192
#define BLOCK  256
#define Q      4                  // queries per wave (wave-uniform)
#define QPB    8                  // queries per block (2 wave-pairs x 4)
#define HALF   4096               // candidates per wave (2-way split)
#define KMASK  0xFFFFFF80
#define EPSV   1e-10f

__device__ __forceinline__ float rfl_f32(float x) {
    // readfirstlane is b32: bit-cast, never numeric-convert
    return __int_as_float(__builtin_amdgcn_readfirstlane(__float_as_int(x)));
}

__device__ __forceinline__ void insert3_idx(float k, int idx,
                                            float& m0, float& m1, float& m2,
                                            int& j0, int& j1, int& j2) {
    const bool c0 = k < m0;
    const bool c1 = k < m1;
    const bool c2 = k < m2;
    m2 = __builtin_amdgcn_fmed3f(k, m1, m2);
    m1 = __builtin_amdgcn_fmed3f(k, m0, m1);
    m0 = fminf(k, m0);
    j2 = c1 ? j1 : (c2 ? idx : j2);
    j1 = c0 ? j0 : (c1 ? idx : j1);
    j0 = c0 ? idx : j0;
}

// pre-kernel: ws[b*NPTS+n] = float4(x1+f1, 0)
__global__ __launch_bounds__(256)
void warp_points_kernel(const float* __restrict__ xyz1,
                        const float* __restrict__ flow1,
                        float4* __restrict__ ws, int total) {
    const int i = blockIdx.x * 256 + threadIdx.x;
    if (i >= total) return;
    const int b = i / NPTS, n = i - b * NPTS;
    const float* x1 = xyz1 + (size_t)b * 3 * NPTS;
    const float* f1 = flow1 + (size_t)b * 3 * NPTS;
    const float px = x1[0*NPTS + n] + f1[0*NPTS + n];
    const float py = x1[1*NPTS + n] + f1[1*NPTS + n];
    const float pz = x1[2*NPTS + n] + f1[2*NPTS + n];
    ws[i] = make_float4(px, py, pz, 0.0f);
}

__global__ __launch_bounds__(BLOCK, 8)
void pointwarp_kernel(const float4* __restrict__ wsp,
                      const float* __restrict__ xyz2,
                      const float* __restrict__ flow1,
                      float* __restrict__ out) {
    __shared__ float s_k[2][2][Q][3];
    __shared__ int   s_i[2][2][Q][3];

    const int tid  = threadIdx.x;
    const int w    = tid >> 6;              // wave in block [0,4)
    const int t    = tid & 63;              // lane
    const int pair = w >> 1;                // query-quad [0,2)
    const int w2   = w & 1;                 // candidate half [0,2)
    const int blocksPerB = NPTS / QPB;      // 1024
    const int b     = blockIdx.x / blocksPerB;
    const int qblk  = (blockIdx.x % blocksPerB) * QPB;
    const int qbase = qblk + pair * Q;

    const float4* cand = wsp + (size_t)b * NPTS;
    const float*  x2   = xyz2 + (size_t)b * 3 * NPTS;
    const float*  f1   = flow1 + (size_t)b * 3 * NPTS;

    // wave-uniform queries -> SGPRs (bit-cast broadcast)
    float qx[Q], qy[Q], qz[Q], k0[Q], k1[Q], k2[Q];
    #pragma unroll
    for (int i = 0; i < Q; ++i) {
        qx[i] = rfl_f32(x2[0*NPTS + qbase + i]);
        qy[i] = rfl_f32(x2[1*NPTS + qbase + i]);
        qz[i] = rfl_f32(x2[2*NPTS + qbase + i]);
        k0[i] = k1[i] = k2[i] = 3e38f;
    }

    // scan this wave's half of the candidates: jj = w2*4096 + j*64 + t
    const float4* base = cand + w2 * HALF + t;
    const int rowbase = w2 * (HALF / 64);
    #pragma unroll 4
    for (int j = 0; j < HALF / 64; ++j) {
        const float4 p = base[j * 64];
        const int jg = rowbase + j;         // wave-uniform row id [0,128)
        #pragma unroll
        for (int i = 0; i < Q; ++i) {
            const float dx = p.x - qx[i];
            const float dy = p.y - qy[i];
            const float dz = p.z - qz[i];
            const float d  = fmaf(dx, dx, fmaf(dy, dy, dz*dz));
            const float k  = __int_as_float((__float_as_int(d) & KMASK) | jg);
            k2[i] = __builtin_amdgcn_fmed3f(k, k1[i], k2[i]);
            k1[i] = __builtin_amdgcn_fmed3f(k, k0[i], k1[i]);
            k0[i] = fminf(k, k0[i]);
        }
    }

    // unpack candidate index: idx = (row << 6) | lane
    int i0[Q], i1[Q], i2[Q];
    #pragma unroll
    for (int i = 0; i < Q; ++i) {
        i0[i] = ((__float_as_int(k0[i]) & 0x7F) << 6) | t;
        i1[i] = ((__float_as_int(k1[i]) & 0x7F) << 6) | t;
        i2[i] = ((__float_as_int(k2[i]) & 0x7F) << 6) | t;
    }

    // wave butterfly merge (64 partial top-3 -> wave top-3)
    #pragma unroll
    for (int step = 1; step < 64; step <<= 1) {
        #pragma unroll
        for (int i = 0; i < Q; ++i) {
            const float b0 = __shfl_xor(k0[i], step, 64);
            const float b1 = __shfl_xor(k1[i], step, 64);
            const float b2 = __shfl_xor(k2[i], step, 64);
            const int   a0 = __shfl_xor(i0[i], step, 64);
            const int   a1 = __shfl_xor(i1[i], step, 64);
            const int   a2 = __shfl_xor(i2[i], step, 64);
            insert3_idx(b0, a0, k0[i], k1[i], k2[i], i0[i], i1[i], i2[i]);
            insert3_idx(b1, a1, k0[i], k1[i], k2[i], i0[i], i1[i], i2[i]);
            insert3_idx(b2, a2, k0[i], k1[i], k2[i], i0[i], i1[i], i2[i]);
        }
    }

    // publish wave results (all lanes identical after butterfly; lane i writes query i)
    #pragma unroll
    for (int i = 0; i < Q; ++i) {
        if (t == i) {
            s_k[pair][w2][i][0] = k0[i]; s_i[pair][w2][i][0] = i0[i];
            s_k[pair][w2][i][1] = k1[i]; s_i[pair][w2][i][1] = i1[i];
            s_k[pair][w2][i][2] = k2[i]; s_i[pair][w2][i][2] = i2[i];
        }
    }
    __syncthreads();

    // one thread per query: merge the two candidate-halves, exact weights, write
    if (tid < QPB) {
        const int u  = tid;
        const int pr = u >> 2, qi = u & 3;
        float m0 = 3e38f, m1 = 3e38f, m2 = 3e38f;
        int   j0 = 0, j1 = 0, j2 = 0;
        #pragma unroll
        for (int wv = 0; wv < 2; ++wv) {
            #pragma unroll
            for (int s = 0; s < 3; ++s) {
                insert3_idx(s_k[pr][wv][qi][s], s_i[pr][wv][qi][s],
                            m0, m1, m2, j0, j1, j2);
            }
        }
        const int n2 = qblk + u;
        const float gx = x2[0*NPTS + n2];
        const float gy = x2[1*NPTS + n2];
        const float gz = x2[2*NPTS + n2];
        float dd[3];
        const int js[3] = {j0, j1, j2};
        #pragma unroll
        for (int s = 0; s < 3; ++s) {
            const float4 p = cand[js[s]];
            const float dx = p.x - gx, dy = p.y - gy, dz = p.z - gz;
            dd[s] = fmaf(dx, dx, fmaf(dy, dy, dz*dz));
        }
        float w0 = 1.0f / fmaxf(sqrtf(dd[0]), EPSV);
        float w1 = 1.0f / fmaxf(sqrtf(dd[1]), EPSV);
        float w2v = 1.0f / fmaxf(sqrtf(dd[2]), EPSV);
        const float ws = w0 + w1 + w2v;
        w0 /= ws; w1 /= ws; w2v /= ws;

        float* o = out + (size_t)b * 3 * NPTS;
        #pragma unroll
        for (int c = 0; c < 3; ++c) {
            const float fl = w0  * f1[c*NPTS + j0]
                           + w1  * f1[c*NPTS + j1]
                           + w2v * f1[c*NPTS + j2];
            o[c*NPTS + n2] = x2[c*NPTS + n2] - fl;
        }
    }
}

extern "C" void kernel_launch(void* const* d_in, const int* in_sizes, int n_in,
                              void* d_out, int out_size, void* d_ws, size_t ws_size,
                              hipStream_t stream) {
    const float* xyz1  = (const float*)d_in[0];
    const float* xyz2  = (const float*)d_in[1];
    const float* flow1 = (const float*)d_in[2];
    float* out = (float*)d_out;
    float4* ws = (float4*)d_ws;

    const int B = in_sizes[0] / (3 * NPTS);       // = 2
    const int total = B * NPTS;
    warp_points_kernel<<<(total + 255) / 256, 256, 0, stream>>>(xyz1, flow1, ws, total);
    const int grid = B * (NPTS / QPB);            // 2048 blocks = 8 per CU
    pointwarp_kernel<<<grid, BLOCK, 0, stream>>>(ws, xyz2, flow1, out);
}

// Round 7
// 97.961 us; speedup vs baseline: 1.6253x; 1.0637x over previous
//
#include <hip/hip_runtime.h>

// PointWarping: B=2, C=3, N=8192. Brute-force K=3 NN + inverse-distance flow interp.
// Round 7: (a) keys-only butterfly merge — indices recovered post-merge by
// ballot-matching final keys against each lane's saved pre-merge top-3
// (the packed key embeds the 7-bit row; lane comes from the ballot), cutting
// merge cost ~4x; (b) 2 candidates per scan iteration (2 independent dwordx4
// loads -> 2x memory-level parallelism for L2 latency hiding).
// Structure from round 6: pre-kernel writes warped points (x1+f1) as float4
// into d_ws (L2-resident); queries wave-uniform in SGPRs; candidates split
// 2-way across wave pairs; grid 2048 blocks; packed keys (25-bit d | 7-bit
// row); exact epilogue recompute.

#define NPTS   8192
#define BLOCK  256
#define Q      4                  // queries per wave (wave-uniform)
#define QPB    8                  // queries per block (2 wave-pairs x 4)
#define HALF   4096               // candidates per wave (2-way split)
#define KMASK  0xFFFFFF80
#define EPSV   1e-10f

__device__ __forceinline__ float rfl_f32(float x) {
    // readfirstlane is b32: bit-cast, never numeric-convert
    return __int_as_float(__builtin_amdgcn_readfirstlane(__float_as_int(x)));
}

// sorted top-3 stream insert, keys only (3 VALU)
__device__ __forceinline__ void ksort3(float k, float& m0, float& m1, float& m2) {
    m2 = __builtin_amdgcn_fmed3f(k, m1, m2);
    m1 = __builtin_amdgcn_fmed3f(k, m0, m1);
    m0 = fminf(k, m0);
}

// sorted top-3 insert with index tracking (epilogue only)
__device__ __forceinline__ void insert3_idx(float k, int idx,
                                            float& m0, float& m1, float& m2,
                                            int& j0, int& j1, int& j2) {
    const bool c0 = k < m0;
    const bool c1 = k < m1;
    const bool c2 = k < m2;
    ksort3(k, m0, m1, m2);
    j2 = c1 ? j1 : (c2 ? idx : j2);
    j1 = c0 ? j0 : (c1 ? idx : j1);
    j0 = c0 ? idx : j0;
}

// pre-kernel: ws[b*NPTS+n] = float4(x1+f1, 0)
__global__ __launch_bounds__(256)
void warp_points_kernel(const float* __restrict__ xyz1,
                        const float* __restrict__ flow1,
                        float4* __restrict__ ws, int total) {
    const int i = blockIdx.x * 256 + threadIdx.x;
    if (i >= total) return;
    const int b = i / NPTS, n = i - b * NPTS;
    const float* x1 = xyz1 + (size_t)b * 3 * NPTS;
    const float* f1 = flow1 + (size_t)b * 3 * NPTS;
    const float px = x1[0*NPTS + n] + f1[0*NPTS + n];
    const float py = x1[1*NPTS + n] + f1[1*NPTS + n];
    const float pz = x1[2*NPTS + n] + f1[2*NPTS + n];
    ws[i] = make_float4(px, py, pz, 0.0f);
}

__global__ __launch_bounds__(BLOCK, 8)
void pointwarp_kernel(const float4* __restrict__ wsp,
                      const float* __restrict__ xyz2,
                      const float* __restrict__ flow1,
                      float* __restrict__ out) {
    __shared__ float s_k[2][2][Q][3];
    __shared__ int   s_i[2][2][Q][3];

    const int tid  = threadIdx.x;
    const int w    = tid >> 6;              // wave in block [0,4)
    const int t    = tid & 63;              // lane
    const int pair = w >> 1;                // query-quad [0,2)
    const int w2   = w & 1;                 // candidate half [0,2)
    const int blocksPerB = NPTS / QPB;      // 1024
    const int b     = blockIdx.x / blocksPerB;
    const int qblk  = (blockIdx.x % blocksPerB) * QPB;
    const int qbase = qblk + pair * Q;

    const float4* cand = wsp + (size_t)b * NPTS;
    const float*  x2   = xyz2 + (size_t)b * 3 * NPTS;
    const float*  f1   = flow1 + (size_t)b * 3 * NPTS;

    // wave-uniform queries -> SGPRs (bit-cast broadcast)
    float qx[Q], qy[Q], qz[Q], k0[Q], k1[Q], k2[Q];
    #pragma unroll
    for (int i = 0; i < Q; ++i) {
        qx[i] = rfl_f32(x2[0*NPTS + qbase + i]);
        qy[i] = rfl_f32(x2[1*NPTS + qbase + i]);
        qz[i] = rfl_f32(x2[2*NPTS + qbase + i]);
        k0[i] = k1[i] = k2[i] = 3e38f;
    }

    // scan this wave's half: 2 candidates per iteration, 2 loads in flight
    const float4* base = cand + w2 * HALF + t;
    const int rowbase = w2 * (HALF / 64);
    #pragma unroll 2
    for (int j = 0; j < HALF / 128; ++j) {
        const float4 p0 = base[j * 128];
        const float4 p1 = base[j * 128 + 64];
        const int jg0 = rowbase + 2*j;       // wave-uniform row ids [0,128)
        const int jg1 = jg0 + 1;
        #pragma unroll
        for (int i = 0; i < Q; ++i) {
            const float dx0 = p0.x - qx[i];
            const float dy0 = p0.y - qy[i];
            const float dz0 = p0.z - qz[i];
            const float d0  = fmaf(dx0, dx0, fmaf(dy0, dy0, dz0*dz0));
            const float ka  = __int_as_float((__float_as_int(d0) & KMASK) | jg0);
            ksort3(ka, k0[i], k1[i], k2[i]);
            const float dx1 = p1.x - qx[i];
            const float dy1 = p1.y - qy[i];
            const float dz1 = p1.z - qz[i];
            const float d1  = fmaf(dx1, dx1, fmaf(dy1, dy1, dz1*dz1));
            const float kb  = __int_as_float((__float_as_int(d1) & KMASK) | jg1);
            ksort3(kb, k0[i], k1[i], k2[i]);
        }
    }

    // save pre-merge per-lane top-3 keys (for index resolution)
    float a0[Q], a1[Q], a2[Q];
    #pragma unroll
    for (int i = 0; i < Q; ++i) { a0[i] = k0[i]; a1[i] = k1[i]; a2[i] = k2[i]; }

    // keys-only butterfly merge: 64 partial top-3 -> wave top-3 (all lanes)
    #pragma unroll
    for (int step = 1; step < 64; step <<= 1) {
        #pragma unroll
        for (int i = 0; i < Q; ++i) {
            const float b0 = __shfl_xor(k0[i], step, 64);
            const float b1 = __shfl_xor(k1[i], step, 64);
            const float b2 = __shfl_xor(k2[i], step, 64);
            ksort3(b0, k0[i], k1[i], k2[i]);
            ksort3(b1, k0[i], k1[i], k2[i]);
            ksort3(b2, k0[i], k1[i], k2[i]);
        }
    }

    // resolve indices: first lane whose pre-merge top-3 contains the final key
    int i0[Q], i1[Q], i2[Q];
    #pragma unroll
    for (int i = 0; i < Q; ++i) {
        {
            const float kf = k0[i];
            const unsigned long long m = __ballot(kf == a0[i] || kf == a1[i] || kf == a2[i]);
            i0[i] = ((__float_as_int(kf) & 0x7F) << 6) | (__ffsll(m) - 1);
        }
        {
            const float kf = k1[i];
            const unsigned long long m = __ballot(kf == a0[i] || kf == a1[i] || kf == a2[i]);
            i1[i] = ((__float_as_int(kf) & 0x7F) << 6) | (__ffsll(m) - 1);
        }
        {
            const float kf = k2[i];
            const unsigned long long m = __ballot(kf == a0[i] || kf == a1[i] || kf == a2[i]);
            i2[i] = ((__float_as_int(kf) & 0x7F) << 6) | (__ffsll(m) - 1);
        }
    }

    // publish wave results (all lanes identical; lane i writes query i)
    #pragma unroll
    for (int i = 0; i < Q; ++i) {
        if (t == i) {
            s_k[pair][w2][i][0] = k0[i]; s_i[pair][w2][i][0] = i0[i];
            s_k[pair][w2][i][1] = k1[i]; s_i[pair][w2][i][1] = i1[i];
            s_k[pair][w2][i][2] = k2[i]; s_i[pair][w2][i][2] = i2[i];
        }
    }
    __syncthreads();

    // one thread per query: merge the two candidate-halves, exact weights, write
    if (tid < QPB) {
        const int u  = tid;
        const int pr = u >> 2, qi = u & 3;
        float m0 = 3e38f, m1 = 3e38f, m2 = 3e38f;
        int   j0 = 0, j1 = 0, j2 = 0;
        #pragma unroll
        for (int wv = 0; wv < 2; ++wv) {
            #pragma unroll
            for (int s = 0; s < 3; ++s) {
                insert3_idx(s_k[pr][wv][qi][s], s_i[pr][wv][qi][s],
                            m0, m1, m2, j0, j1, j2);
            }
        }
        const int n2 = qblk + u;
        const float gx = x2[0*NPTS + n2];
        const float gy = x2[1*NPTS + n2];
        const float gz = x2[2*NPTS + n2];
        float dd[3];
        const int js[3] = {j0, j1, j2};
        #pragma unroll
        for (int s = 0; s < 3; ++s) {
            const float4 p = cand[js[s]];
            const float dx = p.x - gx, dy = p.y - gy, dz = p.z - gz;
            dd[s] = fmaf(dx, dx, fmaf(dy, dy, dz*dz));
        }
        float w0 = 1.0f / fmaxf(sqrtf(dd[0]), EPSV);
        float w1 = 1.0f / fmaxf(sqrtf(dd[1]), EPSV);
        float w2v = 1.0f / fmaxf(sqrtf(dd[2]), EPSV);
        const float ws = w0 + w1 + w2v;
        w0 /= ws; w1 /= ws; w2v /= ws;

        float* o = out + (size_t)b * 3 * NPTS;
        #pragma unroll
        for (int c = 0; c < 3; ++c) {
            const float fl = w0  * f1[c*NPTS + j0]
                           + w1  * f1[c*NPTS + j1]
                           + w2v * f1[c*NPTS + j2];
            o[c*NPTS + n2] = x2[c*NPTS + n2] - fl;
        }
    }
}

extern "C" void kernel_launch(void* const* d_in, const int* in_sizes, int n_in,
                              void* d_out, int out_size, void* d_ws, size_t ws_size,
                              hipStream_t stream) {
    const float* xyz1  = (const float*)d_in[0];
    const float* xyz2  = (const float*)d_in[1];
    const float* flow1 = (const float*)d_in[2];
    float* out = (float*)d_out;
    float4* ws = (float4*)d_ws;

    const int B = in_sizes[0] / (3 * NPTS);       // = 2
    const int total = B * NPTS;
    warp_points_kernel<<<(total + 255) / 256, 256, 0, stream>>>(xyz1, flow1, ws, total);
    const int grid = B * (NPTS / QPB);            // 2048 blocks = 8 per CU
    pointwarp_kernel<<<grid, BLOCK, 0, stream>>>(ws, xyz2, flow1, out);
}